// Round 2
// 284.600 us; speedup vs baseline: 1.0672x; 1.0672x over previous
//
#include <hip/hip_runtime.h>

// Problem constants (fixed by setup_inputs)
static constexpr int Bb = 2, Nn = 128, Ll = 128, Hh = 8, Ee = 64;
static constexpr float SCALE = 0.125f;  // 1/sqrt(E)

typedef short short8 __attribute__((ext_vector_type(8)));   // 8 bf16 in 4 VGPRs
typedef short short4v __attribute__((ext_vector_type(4)));  // 4 bf16 (8 B)
typedef float float4v __attribute__((ext_vector_type(4)));  // MFMA C/D

#define MFMA16(a, b, c) __builtin_amdgcn_mfma_f32_16x16x32_bf16(a, b, c, 0, 0, 0)

__device__ inline unsigned short bf16_rne(float f) {
  unsigned u = __builtin_bit_cast(unsigned, f);
  u += 0x7FFFu + ((u >> 16) & 1u);
  return (unsigned short)(u >> 16);
}

// hi = bf16 truncation, lo = bf16 RNE of residual.  hi*hi + hi*lo + lo*hi
// reconstructs the product to ~2^-15.5 rel.
__device__ inline void split4(float4 a, short4v& hi, short4v& lo) {
  float f[4] = {a.x, a.y, a.z, a.w};
#pragma unroll
  for (int j = 0; j < 4; ++j) {
    unsigned u = __builtin_bit_cast(unsigned, f[j]);
    unsigned short h = (unsigned short)(u >> 16);
    hi[j] = (short)h;
    float hf = __builtin_bit_cast(float, (unsigned)h << 16);
    lo[j] = (short)bf16_rne(f[j] - hf);
  }
}

__device__ inline void split8(float4 a, float4 b, short8& hi, short8& lo) {
  float f[8] = {a.x, a.y, a.z, a.w, b.x, b.y, b.z, b.w};
#pragma unroll
  for (int j = 0; j < 8; ++j) {
    unsigned u = __builtin_bit_cast(unsigned, f[j]);
    unsigned short h = (unsigned short)(u >> 16);
    hi[j] = (short)h;
    float hf = __builtin_bit_cast(float, (unsigned)h << 16);
    lo[j] = (short)bf16_rne(f[j] - hf);
  }
}

__device__ inline short8 pack4(const unsigned* p) {
  union { unsigned u[4]; short8 s; } t;
  t.u[0] = p[0]; t.u[1] = p[1]; t.u[2] = p[2]; t.u[3] = p[3];
  return t.s;  // u32 = 2 consecutive bf16 (low halfword = even k) = frag pair
}

// One block = one 128x128 attention group (b, idx, h).
//   P[r][c] = exp(SCALE * (mask?) * dot(Q[r],K[c]));  Out = (P*V) / rowsum(P)
// Temporal: idx=n, rows=l (stride H*E), mask=null, Out=V_t(ws)
// Spatial : idx=l, rows=n (stride L*H*E), mask[b][r][c], V=V_t
__global__ __launch_bounds__(256, 3) void st_attn(
    const float* __restrict__ Qp, const float* __restrict__ Kp,
    const float* __restrict__ Vp, const float* __restrict__ Mp,
    float* __restrict__ Op, int idx_stride, int row_stride) {
  // Pb is dual-purpose (saves 32 KiB of LDS => keeps 3 blocks/CU):
  //   phase 1: K pre-split bf16 hi/lo planes, fragment-linear + XOR swizzle.
  //            hi plane = u16 [0, 8192), lo plane = u16 [8192, 16384).
  //   phase 2: P (exp'd scores) bf16, row-major stride 130 (16,640 u16).
  __shared__ __align__(16) unsigned short Pb[128 * 130];
  // V^T as bf16: Vb[d][c], stride 130 halfwords.  16,640 B.  Total 49,920 B.
  __shared__ __align__(16) unsigned short Vb[64 * 130];

  const int g = blockIdx.x;
  const int b = g >> 10;
  const int idx = (g >> 3) & 127;
  const int h = g & 7;
  const int base = b * (Nn * Ll * Hh * Ee) + idx * idx_stride + h * Ee;

  const int tid = threadIdx.x;
  const int wave = tid >> 6;
  const int lane = tid & 63;
  const int tx = lane & 15;    // MFMA m/n lane index
  const int quad = lane >> 4;  // MFMA k-chunk / row-quad

  // ---- Stage V -> LDS transposed bf16 (coalesced global reads) ----------
#pragma unroll
  for (int it = 0; it < 8; ++it) {
    const int i4 = tid + it * 256;     // 0..2047
    const int c = i4 >> 4;             // V row 0..127
    const int d0 = (i4 & 15) << 2;     // V col 0..60
    const float4 v = *(const float4*)(Vp + base + c * row_stride + d0);
    Vb[(d0 + 0) * 130 + c] = bf16_rne(v.x);
    Vb[(d0 + 1) * 130 + c] = bf16_rne(v.y);
    Vb[(d0 + 2) * 130 + c] = bf16_rne(v.z);
    Vb[(d0 + 3) * 130 + c] = bf16_rne(v.w);
  }

  // ---- Stage K -> LDS once per block (was: 4x redundant per-wave global
  // loads + splits).  Element K[r][d]: fragment F = ((r>>4)*8+(d>>3))*16+(r&15)
  // holds the 8 consecutive d of one B-fragment lane; swizzle F' = F^(d>>3)
  // spreads the 128B-strided fragment reads across all bank groups.
  // u16 index = F'*8 + (d&7); lo-residual plane at +8192 u16 (16,384 B).
#pragma unroll
  for (int it = 0; it < 8; ++it) {
    const int i4 = tid + it * 256;     // 0..2047
    const int r = i4 >> 4;             // K row 0..127
    const int d0 = (i4 & 15) << 2;     // K col 0..60
    const float4 kv = *(const float4*)(Kp + base + r * row_stride + d0);
    const int vs = d0 >> 3;            // ks*4+quad of this chunk, 0..7
    const int idxk =
        ((((r >> 4) * 8 + vs) * 16 + (r & 15)) ^ vs) * 8 + (d0 & 7);
    short4v h4, l4;
    split4(kv, h4, l4);
    *(short4v*)(Pb + idxk) = h4;
    *(short4v*)(Pb + idxk + 8192) = l4;
  }

  // ---- Q fragments (direct global, hi/lo split), rows 32w..32w+31 -------
  short8 qhi[2][2], qlo[2][2];
#pragma unroll
  for (int rt = 0; rt < 2; ++rt) {
    const float* qr = Qp + base + (wave * 32 + rt * 16 + tx) * row_stride;
#pragma unroll
    for (int ks = 0; ks < 2; ++ks) {
      const float4 a = *(const float4*)(qr + ks * 32 + quad * 8);
      const float4 c = *(const float4*)(qr + ks * 32 + quad * 8 + 4);
      split8(a, c, qhi[rt][ks], qlo[rt][ks]);
    }
  }

  __syncthreads();  // K + V staged

  // ---- Score GEMM: S = Q*K^T from LDS K fragments (conflict-free b128) --
  float4v acc[2][8];
#pragma unroll
  for (int rt = 0; rt < 2; ++rt)
#pragma unroll
    for (int ct = 0; ct < 8; ++ct) acc[rt][ct] = (float4v)(0.0f);

  const short8* KS8 = (const short8*)Pb;
#pragma unroll
  for (int ct = 0; ct < 8; ++ct) {
#pragma unroll
    for (int ks = 0; ks < 2; ++ks) {
      const int vs = ks * 4 + quad;
      const int fi = (((ct * 8 + vs) * 16 + tx) ^ vs);
      const short8 khi = KS8[fi];
      const short8 klo = KS8[fi + 1024];  // lo plane: +1024 frags = +16,384 B
#pragma unroll
      for (int rt = 0; rt < 2; ++rt) {
        acc[rt][ct] = MFMA16(qhi[rt][ks], khi, acc[rt][ct]);
        acc[rt][ct] = MFMA16(qhi[rt][ks], klo, acc[rt][ct]);
        acc[rt][ct] = MFMA16(qlo[rt][ks], khi, acc[rt][ct]);
      }
    }
  }

  // ---- Softmax: scale/mask/exp in-place (registers), fp32 rowsums -------
  const bool has_mask = (Mp != nullptr);
  const int mb = b * (Nn * Nn);
  float rowsum[2][4];
#pragma unroll
  for (int rt = 0; rt < 2; ++rt)
#pragma unroll
    for (int e = 0; e < 4; ++e) rowsum[rt][e] = 0.f;

#pragma unroll
  for (int rt = 0; rt < 2; ++rt) {
    const int rowb = wave * 32 + rt * 16 + quad * 4;  // C/D row = quad*4+reg
#pragma unroll
    for (int ct = 0; ct < 8; ++ct) {
      const int col = ct * 16 + tx;  // C/D col = lane&15
      float mv[4];
      if (has_mask) {
#pragma unroll
        for (int e = 0; e < 4; ++e) mv[e] = Mp[mb + (rowb + e) * 128 + col];
      }
#pragma unroll
      for (int e = 0; e < 4; ++e) {
        float p = acc[rt][ct][e] * SCALE;
        if (has_mask) p *= mv[e];
        p = __expf(p);
        rowsum[rt][e] += p;   // exact fp32 denominator (pre-rounding)
        acc[rt][ct][e] = p;   // keep P in registers until Pb is free
      }
    }
  }

  // Row sums complete across the 16 tx lanes of each quad group.
  float inv[2][4];
#pragma unroll
  for (int rt = 0; rt < 2; ++rt)
#pragma unroll
    for (int e = 0; e < 4; ++e) {
      float s = rowsum[rt][e];
#pragma unroll
      for (int d = 1; d < 16; d <<= 1) s += __shfl_xor(s, d);
      inv[rt][e] = 1.0f / s;
    }

  __syncthreads();  // all waves done reading K fragments -> Pb reusable

  // ---- P -> LDS bf16, row-major stride 130 ------------------------------
#pragma unroll
  for (int rt = 0; rt < 2; ++rt) {
    const int rowb = wave * 32 + rt * 16 + quad * 4;
#pragma unroll
    for (int ct = 0; ct < 8; ++ct) {
      const int col = ct * 16 + tx;
#pragma unroll
      for (int e = 0; e < 4; ++e)
        Pb[(rowb + e) * 130 + col] = bf16_rne(acc[rt][ct][e]);
    }
  }

  __syncthreads();  // Pb fully written (Vb staged long ago)

  // ---- PV GEMM: O = P*V, A = P rows (this wave's own), B = V^T rows -----
  float4v accO[2][4];
#pragma unroll
  for (int rt = 0; rt < 2; ++rt)
#pragma unroll
    for (int dt = 0; dt < 4; ++dt) accO[rt][dt] = (float4v)(0.0f);

#pragma unroll
  for (int ks = 0; ks < 4; ++ks) {
    short8 pA[2];
#pragma unroll
    for (int rt = 0; rt < 2; ++rt) {
      const unsigned* pw = (const unsigned*)Pb +
                           (wave * 32 + rt * 16 + tx) * 65 + ks * 16 + quad * 4;
      pA[rt] = pack4(pw);
    }
#pragma unroll
    for (int dt = 0; dt < 4; ++dt) {
      const unsigned* vw =
          (const unsigned*)Vb + (dt * 16 + tx) * 65 + ks * 16 + quad * 4;
      const short8 vB = pack4(vw);
      accO[0][dt] = MFMA16(pA[0], vB, accO[0][dt]);
      accO[1][dt] = MFMA16(pA[1], vB, accO[1][dt]);
    }
  }

  // ---- Normalize + store ------------------------------------------------
#pragma unroll
  for (int rt = 0; rt < 2; ++rt) {
    const int rowb = wave * 32 + rt * 16 + quad * 4;
#pragma unroll
    for (int dt = 0; dt < 4; ++dt) {
#pragma unroll
      for (int e = 0; e < 4; ++e) {
        Op[base + (rowb + e) * row_stride + dt * 16 + tx] =
            accO[rt][dt][e] * inv[rt][e];
      }
    }
  }
}

extern "C" void kernel_launch(void* const* d_in, const int* in_sizes, int n_in,
                              void* d_out, int out_size, void* d_ws,
                              size_t ws_size, hipStream_t stream) {
  const float* Q = (const float*)d_in[0];
  const float* K = (const float*)d_in[1];
  const float* V = (const float*)d_in[2];
  const float* M = (const float*)d_in[3];
  float* out = (float*)d_out;
  float* Vt = (float*)d_ws;  // 64 MiB intermediate V_t in workspace

  dim3 grid(Bb * Nn * Hh), blk(256);  // 2048 blocks
  // Temporal: per (b,n,h), rows = l
  st_attn<<<grid, blk, 0, stream>>>(Q, K, V, nullptr, Vt,
                                    Ll * Hh * Ee /*n stride*/,
                                    Hh * Ee /*l stride*/);
  // Spatial: per (b,l,h), rows = n, V operand = V_t
  st_attn<<<grid, blk, 0, stream>>>(Q, K, Vt, M, out, Hh * Ee /*l stride*/,
                                    Ll * Hh * Ee /*n stride*/);
}

// Round 3
// 278.141 us; speedup vs baseline: 1.0920x; 1.0232x over previous
//
#include <hip/hip_runtime.h>

// Problem constants (fixed by setup_inputs)
static constexpr int Bb = 2, Nn = 128, Ll = 128, Hh = 8, Ee = 64;
static constexpr float SCALE = 0.125f;  // 1/sqrt(E)

typedef short short8 __attribute__((ext_vector_type(8)));   // 8 bf16 in 4 VGPRs
typedef short short4v __attribute__((ext_vector_type(4)));  // 4 bf16 (8 B)
typedef float float4v __attribute__((ext_vector_type(4)));  // MFMA C/D

#define MFMA16(a, b, c) __builtin_amdgcn_mfma_f32_16x16x32_bf16(a, b, c, 0, 0, 0)

__device__ inline unsigned short bf16_rne(float f) {
  unsigned u = __builtin_bit_cast(unsigned, f);
  u += 0x7FFFu + ((u >> 16) & 1u);
  return (unsigned short)(u >> 16);
}

// hi = bf16 truncation, lo = bf16 RNE of residual.  hi*hi + hi*lo + lo*hi
// reconstructs the product to ~2^-15.5 rel.
__device__ inline void split4(float4 a, short4v& hi, short4v& lo) {
  float f[4] = {a.x, a.y, a.z, a.w};
#pragma unroll
  for (int j = 0; j < 4; ++j) {
    unsigned u = __builtin_bit_cast(unsigned, f[j]);
    unsigned short h = (unsigned short)(u >> 16);
    hi[j] = (short)h;
    float hf = __builtin_bit_cast(float, (unsigned)h << 16);
    lo[j] = (short)bf16_rne(f[j] - hf);
  }
}

__device__ inline void split8(float4 a, float4 b, short8& hi, short8& lo) {
  float f[8] = {a.x, a.y, a.z, a.w, b.x, b.y, b.z, b.w};
#pragma unroll
  for (int j = 0; j < 8; ++j) {
    unsigned u = __builtin_bit_cast(unsigned, f[j]);
    unsigned short h = (unsigned short)(u >> 16);
    hi[j] = (short)h;
    float hf = __builtin_bit_cast(float, (unsigned)h << 16);
    lo[j] = (short)bf16_rne(f[j] - hf);
  }
}

__device__ inline short8 pack4(const unsigned* p) {
  union { unsigned u[4]; short8 s; } t;
  t.u[0] = p[0]; t.u[1] = p[1]; t.u[2] = p[2]; t.u[3] = p[3];
  return t.s;  // u32 = 2 consecutive bf16 (low halfword = even k) = frag pair
}

// One block = one 128x128 attention group (b, idx, h).
//   P[r][c] = exp(SCALE * (mask?) * dot(Q[r],K[c]));  Out = (P*V) / rowsum(P)
// Temporal: idx=n, rows=l (stride H*E), mask=null, Out=V_t(ws)
// Spatial : idx=l, rows=n (stride L*H*E), mask[b][r][c], V=V_t
__global__ __launch_bounds__(256, 3) void st_attn(
    const float* __restrict__ Qp, const float* __restrict__ Kp,
    const float* __restrict__ Vp, const float* __restrict__ Mp,
    float* __restrict__ Op, int idx_stride, int row_stride) {
  // Pb is dual-purpose (saves 32 KiB of LDS => keeps 3 blocks/CU):
  //   phase 1: K pre-split bf16 hi/lo planes, fragment-linear + XOR swizzle.
  //            hi plane = u16 [0, 8192), lo plane = u16 [8192, 16384).
  //   phase 2: P (exp'd scores) bf16, row-major stride 130 (16,640 u16).
  __shared__ __align__(16) unsigned short Pb[128 * 130];
  // V^T as bf16: Vb[d][c], stride 130 halfwords.  16,640 B.  Total 49,920 B.
  __shared__ __align__(16) unsigned short Vb[64 * 130];

  const int g = blockIdx.x;
  const int b = g >> 10;
  const int idx = (g >> 3) & 127;
  const int h = g & 7;
  const int base = b * (Nn * Ll * Hh * Ee) + idx * idx_stride + h * Ee;

  const int tid = threadIdx.x;
  const int wave = tid >> 6;
  const int lane = tid & 63;
  const int tx = lane & 15;    // MFMA m/n lane index
  const int quad = lane >> 4;  // MFMA k-chunk / row-quad

  // ======== MLP phase: issue ALL staging loads into distinct registers ====
  // (Round-2 lesson: VGPR=76 => compiler had chained load->convert->reuse,
  //  serializing ~24 HBM latencies per thread.  Buffer arrays force all
  //  loads in flight; peak live set ~96 VGPR, fits the 170 budget of
  //  launch_bounds(256,3).)
  float4 vL[8], kL[8], qL[8];
#pragma unroll
  for (int it = 0; it < 8; ++it) {
    const int i4 = tid + it * 256;  // 0..2047
    vL[it] = *(const float4*)(Vp + base + (i4 >> 4) * row_stride +
                              ((i4 & 15) << 2));
  }
#pragma unroll
  for (int it = 0; it < 8; ++it) {
    const int i4 = tid + it * 256;
    kL[it] = *(const float4*)(Kp + base + (i4 >> 4) * row_stride +
                              ((i4 & 15) << 2));
  }
#pragma unroll
  for (int rt = 0; rt < 2; ++rt) {
    const float* qr = Qp + base + (wave * 32 + rt * 16 + tx) * row_stride;
#pragma unroll
    for (int ks = 0; ks < 2; ++ks) {
      qL[(rt * 2 + ks) * 2 + 0] = *(const float4*)(qr + ks * 32 + quad * 8);
      qL[(rt * 2 + ks) * 2 + 1] =
          *(const float4*)(qr + ks * 32 + quad * 8 + 4);
    }
  }

  // ---- Consume V: LDS transposed bf16 ------------------------------------
#pragma unroll
  for (int it = 0; it < 8; ++it) {
    const int i4 = tid + it * 256;
    const int c = i4 >> 4;             // V row 0..127
    const int d0 = (i4 & 15) << 2;     // V col 0..60
    const float4 v = vL[it];
    Vb[(d0 + 0) * 130 + c] = bf16_rne(v.x);
    Vb[(d0 + 1) * 130 + c] = bf16_rne(v.y);
    Vb[(d0 + 2) * 130 + c] = bf16_rne(v.z);
    Vb[(d0 + 3) * 130 + c] = bf16_rne(v.w);
  }

  // ---- Consume K: pre-split hi/lo planes, fragment-linear + XOR swizzle --
  // Element K[r][d]: fragment F = ((r>>4)*8+(d>>3))*16+(r&15); F' = F^(d>>3).
  // u16 index = F'*8 + (d&7); lo plane at +8192 u16.
#pragma unroll
  for (int it = 0; it < 8; ++it) {
    const int i4 = tid + it * 256;
    const int r = i4 >> 4;             // K row 0..127
    const int d0 = (i4 & 15) << 2;     // K col 0..60
    const int vs = d0 >> 3;            // ks*4+quad of this chunk, 0..7
    const int idxk =
        ((((r >> 4) * 8 + vs) * 16 + (r & 15)) ^ vs) * 8 + (d0 & 7);
    short4v h4, l4;
    split4(kL[it], h4, l4);
    *(short4v*)(Pb + idxk) = h4;
    *(short4v*)(Pb + idxk + 8192) = l4;
  }

  // ---- Consume Q: hi/lo split fragments ----------------------------------
  short8 qhi[2][2], qlo[2][2];
#pragma unroll
  for (int rt = 0; rt < 2; ++rt)
#pragma unroll
    for (int ks = 0; ks < 2; ++ks)
      split8(qL[(rt * 2 + ks) * 2 + 0], qL[(rt * 2 + ks) * 2 + 1],
             qhi[rt][ks], qlo[rt][ks]);

  __syncthreads();  // K + V staged

  // ---- Score GEMM: S = Q*K^T from LDS K fragments (conflict-free b128) --
  float4v acc[2][8];
#pragma unroll
  for (int rt = 0; rt < 2; ++rt)
#pragma unroll
    for (int ct = 0; ct < 8; ++ct) acc[rt][ct] = (float4v)(0.0f);

  const short8* KS8 = (const short8*)Pb;
#pragma unroll
  for (int ct = 0; ct < 8; ++ct) {
#pragma unroll
    for (int ks = 0; ks < 2; ++ks) {
      const int vs = ks * 4 + quad;
      const int fi = (((ct * 8 + vs) * 16 + tx) ^ vs);
      const short8 khi = KS8[fi];
      const short8 klo = KS8[fi + 1024];  // lo plane: +1024 frags
#pragma unroll
      for (int rt = 0; rt < 2; ++rt) {
        acc[rt][ct] = MFMA16(qhi[rt][ks], khi, acc[rt][ct]);
        acc[rt][ct] = MFMA16(qhi[rt][ks], klo, acc[rt][ct]);
        acc[rt][ct] = MFMA16(qlo[rt][ks], khi, acc[rt][ct]);
      }
    }
  }

  // ---- Softmax: scale/mask/exp in registers, fp32 rowsums ---------------
  const bool has_mask = (Mp != nullptr);
  const int mb = b * (Nn * Nn);
  float rowsum[2][4];
#pragma unroll
  for (int rt = 0; rt < 2; ++rt)
#pragma unroll
    for (int e = 0; e < 4; ++e) rowsum[rt][e] = 0.f;

#pragma unroll
  for (int rt = 0; rt < 2; ++rt) {
    const int rowb = wave * 32 + rt * 16 + quad * 4;  // C/D row = quad*4+reg
    // Issue ALL mask loads for this rt before the exp loop (32 in flight).
    float mv[8][4];
    if (has_mask) {
#pragma unroll
      for (int ct = 0; ct < 8; ++ct)
#pragma unroll
        for (int e = 0; e < 4; ++e)
          mv[ct][e] = Mp[mb + (rowb + e) * 128 + ct * 16 + tx];
    }
#pragma unroll
    for (int ct = 0; ct < 8; ++ct) {
#pragma unroll
      for (int e = 0; e < 4; ++e) {
        float p = acc[rt][ct][e] * SCALE;
        if (has_mask) p *= mv[ct][e];
        p = __expf(p);
        rowsum[rt][e] += p;   // exact fp32 denominator (pre-rounding)
        acc[rt][ct][e] = p;   // keep P in registers until Pb is free
      }
    }
  }

  // Row sums complete across the 16 tx lanes of each quad group.
  float inv[2][4];
#pragma unroll
  for (int rt = 0; rt < 2; ++rt)
#pragma unroll
    for (int e = 0; e < 4; ++e) {
      float s = rowsum[rt][e];
#pragma unroll
      for (int d = 1; d < 16; d <<= 1) s += __shfl_xor(s, d);
      inv[rt][e] = 1.0f / s;
    }

  __syncthreads();  // all waves done reading K fragments -> Pb reusable

  // ---- P -> LDS bf16, row-major stride 130 ------------------------------
#pragma unroll
  for (int rt = 0; rt < 2; ++rt) {
    const int rowb = wave * 32 + rt * 16 + quad * 4;
#pragma unroll
    for (int ct = 0; ct < 8; ++ct) {
      const int col = ct * 16 + tx;
#pragma unroll
      for (int e = 0; e < 4; ++e)
        Pb[(rowb + e) * 130 + col] = bf16_rne(acc[rt][ct][e]);
    }
  }

  __syncthreads();  // Pb fully written (Vb staged long ago)

  // ---- PV GEMM: O = P*V, A = P rows (this wave's own), B = V^T rows -----
  float4v accO[2][4];
#pragma unroll
  for (int rt = 0; rt < 2; ++rt)
#pragma unroll
    for (int dt = 0; dt < 4; ++dt) accO[rt][dt] = (float4v)(0.0f);

#pragma unroll
  for (int ks = 0; ks < 4; ++ks) {
    short8 pA[2];
#pragma unroll
    for (int rt = 0; rt < 2; ++rt) {
      const unsigned* pw = (const unsigned*)Pb +
                           (wave * 32 + rt * 16 + tx) * 65 + ks * 16 + quad * 4;
      pA[rt] = pack4(pw);
    }
#pragma unroll
    for (int dt = 0; dt < 4; ++dt) {
      const unsigned* vw =
          (const unsigned*)Vb + (dt * 16 + tx) * 65 + ks * 16 + quad * 4;
      const short8 vB = pack4(vw);
      accO[0][dt] = MFMA16(pA[0], vB, accO[0][dt]);
      accO[1][dt] = MFMA16(pA[1], vB, accO[1][dt]);
    }
  }

  // ---- Normalize + store ------------------------------------------------
#pragma unroll
  for (int rt = 0; rt < 2; ++rt) {
    const int rowb = wave * 32 + rt * 16 + quad * 4;
#pragma unroll
    for (int dt = 0; dt < 4; ++dt) {
#pragma unroll
      for (int e = 0; e < 4; ++e) {
        Op[base + (rowb + e) * row_stride + dt * 16 + tx] =
            accO[rt][dt][e] * inv[rt][e];
      }
    }
  }
}

extern "C" void kernel_launch(void* const* d_in, const int* in_sizes, int n_in,
                              void* d_out, int out_size, void* d_ws,
                              size_t ws_size, hipStream_t stream) {
  const float* Q = (const float*)d_in[0];
  const float* K = (const float*)d_in[1];
  const float* V = (const float*)d_in[2];
  const float* M = (const float*)d_in[3];
  float* out = (float*)d_out;
  float* Vt = (float*)d_ws;  // 64 MiB intermediate V_t in workspace

  dim3 grid(Bb * Nn * Hh), blk(256);  // 2048 blocks
  // Temporal: per (b,n,h), rows = l
  st_attn<<<grid, blk, 0, stream>>>(Q, K, V, nullptr, Vt,
                                    Ll * Hh * Ee /*n stride*/,
                                    Hh * Ee /*l stride*/);
  // Spatial: per (b,l,h), rows = n, V operand = V_t
  st_attn<<<grid, blk, 0, stream>>>(Q, K, Vt, M, out, Hh * Ee /*l stride*/,
                                    Ll * Hh * Ee /*n stride*/);
}

// Round 4
// 275.854 us; speedup vs baseline: 1.1010x; 1.0083x over previous
//
#include <hip/hip_runtime.h>

// Problem constants (fixed by setup_inputs)
static constexpr int Bb = 2, Nn = 128, Ll = 128, Hh = 8, Ee = 64;
static constexpr float SCALE = 0.125f;  // 1/sqrt(E)

typedef short short8 __attribute__((ext_vector_type(8)));   // 8 bf16 in 4 VGPRs
typedef short short4v __attribute__((ext_vector_type(4)));  // 4 bf16 (8 B)
typedef float float4v __attribute__((ext_vector_type(4)));  // MFMA C/D

#define MFMA16(a, b, c) __builtin_amdgcn_mfma_f32_16x16x32_bf16(a, b, c, 0, 0, 0)

__device__ inline unsigned short bf16_rne(float f) {
  unsigned u = __builtin_bit_cast(unsigned, f);
  u += 0x7FFFu + ((u >> 16) & 1u);
  return (unsigned short)(u >> 16);
}

// hi = bf16 truncation, lo = bf16 RNE of residual.  hi*hi + hi*lo + lo*hi
// reconstructs the product to ~2^-15.5 rel.
__device__ inline void split4(float4 a, short4v& hi, short4v& lo) {
  float f[4] = {a.x, a.y, a.z, a.w};
#pragma unroll
  for (int j = 0; j < 4; ++j) {
    unsigned u = __builtin_bit_cast(unsigned, f[j]);
    unsigned short h = (unsigned short)(u >> 16);
    hi[j] = (short)h;
    float hf = __builtin_bit_cast(float, (unsigned)h << 16);
    lo[j] = (short)bf16_rne(f[j] - hf);
  }
}

__device__ inline void split8(float4 a, float4 b, short8& hi, short8& lo) {
  float f[8] = {a.x, a.y, a.z, a.w, b.x, b.y, b.z, b.w};
#pragma unroll
  for (int j = 0; j < 8; ++j) {
    unsigned u = __builtin_bit_cast(unsigned, f[j]);
    unsigned short h = (unsigned short)(u >> 16);
    hi[j] = (short)h;
    float hf = __builtin_bit_cast(float, (unsigned)h << 16);
    lo[j] = (short)bf16_rne(f[j] - hf);
  }
}

__device__ inline short8 pack4(const unsigned* p) {
  union { unsigned u[4]; short8 s; } t;
  t.u[0] = p[0]; t.u[1] = p[1]; t.u[2] = p[2]; t.u[3] = p[3];
  return t.s;  // u32 = 2 consecutive bf16 (low halfword = even k) = frag pair
}

// One block = one 128x128 attention group (b, idx, h), EIGHT waves.
// Round-4 restructure: 512 threads/block, each wave owns 16 rows (was 32).
// Per-wave serial chains halve; resident waves/CU double (12 -> 24) while
// LDS (the occupancy limiter at 50 KB -> 3 blocks/CU) is unchanged.
//   P[r][c] = exp(SCALE * (mask?) * dot(Q[r],K[c]));  Out = (P*V) / rowsum(P)
// Temporal: idx=n, rows=l (stride H*E), mask=null, Out=V_t(ws)
// Spatial : idx=l, rows=n (stride L*H*E), mask[b][r][c], V=V_t
__global__ __launch_bounds__(512, 6) void st_attn(
    const float* __restrict__ Qp, const float* __restrict__ Kp,
    const float* __restrict__ Vp, const float* __restrict__ Mp,
    float* __restrict__ Op, int idx_stride, int row_stride) {
  // Pb is dual-purpose:
  //   phase 1: K pre-split bf16 hi/lo planes, fragment-linear + XOR swizzle.
  //            hi plane = u16 [0, 8192), lo plane = u16 [8192, 16384).
  //   phase 2: P (exp'd scores) bf16, row-major stride 130 (16,640 u16).
  __shared__ __align__(16) unsigned short Pb[128 * 130];
  // V^T as bf16: Vb[d][c], stride 130 halfwords.  Total 49,920 B.
  __shared__ __align__(16) unsigned short Vb[64 * 130];

  const int g = blockIdx.x;
  const int b = g >> 10;
  const int idx = (g >> 3) & 127;
  const int h = g & 7;
  const int base = b * (Nn * Ll * Hh * Ee) + idx * idx_stride + h * Ee;

  const int tid = threadIdx.x;
  const int wave = tid >> 6;   // 0..7
  const int lane = tid & 63;
  const int tx = lane & 15;    // MFMA m/n lane index
  const int quad = lane >> 4;  // MFMA k-chunk / row-quad
  const int rowbase = wave * 16;  // this wave's 16 output rows

  // ---- Issue staging loads into register buffers (4+4+4 per thread) ------
  float4 vL[4], kL[4], qL[4];
#pragma unroll
  for (int it = 0; it < 4; ++it) {
    const int i4 = tid + it * 512;  // 0..2047
    vL[it] = *(const float4*)(Vp + base + (i4 >> 4) * row_stride +
                              ((i4 & 15) << 2));
  }
#pragma unroll
  for (int it = 0; it < 4; ++it) {
    const int i4 = tid + it * 512;
    kL[it] = *(const float4*)(Kp + base + (i4 >> 4) * row_stride +
                              ((i4 & 15) << 2));
  }
  {
    const float* qr = Qp + base + (rowbase + tx) * row_stride;
#pragma unroll
    for (int ks = 0; ks < 2; ++ks) {
      qL[ks * 2 + 0] = *(const float4*)(qr + ks * 32 + quad * 8);
      qL[ks * 2 + 1] = *(const float4*)(qr + ks * 32 + quad * 8 + 4);
    }
  }

  // ---- Consume V: LDS transposed bf16 ------------------------------------
#pragma unroll
  for (int it = 0; it < 4; ++it) {
    const int i4 = tid + it * 512;
    const int c = i4 >> 4;             // V row 0..127
    const int d0 = (i4 & 15) << 2;     // V col 0..60
    const float4 v = vL[it];
    Vb[(d0 + 0) * 130 + c] = bf16_rne(v.x);
    Vb[(d0 + 1) * 130 + c] = bf16_rne(v.y);
    Vb[(d0 + 2) * 130 + c] = bf16_rne(v.z);
    Vb[(d0 + 3) * 130 + c] = bf16_rne(v.w);
  }

  // ---- Consume K: pre-split hi/lo planes, fragment-linear + XOR swizzle --
  // Element K[r][d]: fragment F = ((r>>4)*8+(d>>3))*16+(r&15); F' = F^(d>>3).
  // u16 index = F'*8 + (d&7); lo plane at +8192 u16.
#pragma unroll
  for (int it = 0; it < 4; ++it) {
    const int i4 = tid + it * 512;
    const int r = i4 >> 4;             // K row 0..127
    const int d0 = (i4 & 15) << 2;     // K col 0..60
    const int vs = d0 >> 3;            // ks*4+quad of this chunk, 0..7
    const int idxk =
        ((((r >> 4) * 8 + vs) * 16 + (r & 15)) ^ vs) * 8 + (d0 & 7);
    short4v h4, l4;
    split4(kL[it], h4, l4);
    *(short4v*)(Pb + idxk) = h4;
    *(short4v*)(Pb + idxk + 8192) = l4;
  }

  // ---- Consume Q: hi/lo split fragments ----------------------------------
  short8 qhi[2], qlo[2];
#pragma unroll
  for (int ks = 0; ks < 2; ++ks)
    split8(qL[ks * 2 + 0], qL[ks * 2 + 1], qhi[ks], qlo[ks]);

  __syncthreads();  // K + V staged

  // ---- Score GEMM: S = Q*K^T from LDS K fragments (conflict-free b128) --
  float4v acc[8];
#pragma unroll
  for (int ct = 0; ct < 8; ++ct) acc[ct] = (float4v)(0.0f);

  const short8* KS8 = (const short8*)Pb;
#pragma unroll
  for (int ct = 0; ct < 8; ++ct) {
#pragma unroll
    for (int ks = 0; ks < 2; ++ks) {
      const int vs = ks * 4 + quad;
      const int fi = (((ct * 8 + vs) * 16 + tx) ^ vs);
      const short8 khi = KS8[fi];
      const short8 klo = KS8[fi + 1024];  // lo plane: +1024 frags
      acc[ct] = MFMA16(qhi[ks], khi, acc[ct]);
      acc[ct] = MFMA16(qhi[ks], klo, acc[ct]);
      acc[ct] = MFMA16(qlo[ks], khi, acc[ct]);
    }
  }

  // ---- Softmax: scale/mask/exp in registers, fp32 rowsums ---------------
  const bool has_mask = (Mp != nullptr);
  const int mb = b * (Nn * Nn);
  const int rowb = rowbase + quad * 4;  // C/D row = quad*4+e
  float rowsum[4] = {0.f, 0.f, 0.f, 0.f};

  float mv[8][4];
  if (has_mask) {
#pragma unroll
    for (int ct = 0; ct < 8; ++ct)
#pragma unroll
      for (int e = 0; e < 4; ++e)
        mv[ct][e] = Mp[mb + (rowb + e) * 128 + ct * 16 + tx];
  }
#pragma unroll
  for (int ct = 0; ct < 8; ++ct) {
#pragma unroll
    for (int e = 0; e < 4; ++e) {
      float p = acc[ct][e] * SCALE;
      if (has_mask) p *= mv[ct][e];
      p = __expf(p);
      rowsum[e] += p;   // exact fp32 denominator (pre-rounding)
      acc[ct][e] = p;   // keep P in registers until Pb is free
    }
  }

  // Row sums complete across the 16 tx lanes of each quad group.
  float inv[4];
#pragma unroll
  for (int e = 0; e < 4; ++e) {
    float s = rowsum[e];
#pragma unroll
    for (int d = 1; d < 16; d <<= 1) s += __shfl_xor(s, d);
    inv[e] = 1.0f / s;
  }

  __syncthreads();  // all waves done reading K fragments -> Pb reusable

  // ---- P -> LDS bf16, row-major stride 130 ------------------------------
#pragma unroll
  for (int ct = 0; ct < 8; ++ct) {
    const int col = ct * 16 + tx;
#pragma unroll
    for (int e = 0; e < 4; ++e)
      Pb[(rowb + e) * 130 + col] = bf16_rne(acc[ct][e]);
  }

  __syncthreads();  // Pb fully written (Vb staged long ago)

  // ---- PV GEMM: O = P*V, A = P rows (this wave's own 16), B = V^T rows --
  float4v accO[4];
#pragma unroll
  for (int dt = 0; dt < 4; ++dt) accO[dt] = (float4v)(0.0f);

#pragma unroll
  for (int ks = 0; ks < 4; ++ks) {
    const unsigned* pw =
        (const unsigned*)Pb + (rowbase + tx) * 65 + ks * 16 + quad * 4;
    const short8 pA = pack4(pw);
#pragma unroll
    for (int dt = 0; dt < 4; ++dt) {
      const unsigned* vw =
          (const unsigned*)Vb + (dt * 16 + tx) * 65 + ks * 16 + quad * 4;
      const short8 vB = pack4(vw);
      accO[dt] = MFMA16(pA, vB, accO[dt]);
    }
  }

  // ---- Normalize + store ------------------------------------------------
#pragma unroll
  for (int dt = 0; dt < 4; ++dt) {
#pragma unroll
    for (int e = 0; e < 4; ++e) {
      Op[base + (rowb + e) * row_stride + dt * 16 + tx] =
          accO[dt][e] * inv[e];
    }
  }
}

extern "C" void kernel_launch(void* const* d_in, const int* in_sizes, int n_in,
                              void* d_out, int out_size, void* d_ws,
                              size_t ws_size, hipStream_t stream) {
  const float* Q = (const float*)d_in[0];
  const float* K = (const float*)d_in[1];
  const float* V = (const float*)d_in[2];
  const float* M = (const float*)d_in[3];
  float* out = (float*)d_out;
  float* Vt = (float*)d_ws;  // 64 MiB intermediate V_t in workspace

  dim3 grid(Bb * Nn * Hh), blk(512);  // 2048 blocks x 8 waves
  // Temporal: per (b,n,h), rows = l
  st_attn<<<grid, blk, 0, stream>>>(Q, K, V, nullptr, Vt,
                                    Ll * Hh * Ee /*n stride*/,
                                    Hh * Ee /*l stride*/);
  // Spatial: per (b,l,h), rows = n, V operand = V_t
  st_attn<<<grid, blk, 0, stream>>>(Q, K, Vt, M, out, Hh * Ee /*l stride*/,
                                    Ll * Hh * Ee /*n stride*/);
}

// Round 5
// 275.777 us; speedup vs baseline: 1.1013x; 1.0003x over previous
//
#include <hip/hip_runtime.h>

// Problem constants (fixed by setup_inputs)
static constexpr int Bb = 2, Nn = 128, Ll = 128, Hh = 8, Ee = 64;
static constexpr float SCALE = 0.125f;  // 1/sqrt(E)

typedef short short8 __attribute__((ext_vector_type(8)));   // 8 bf16 in 4 VGPRs
typedef short short4v __attribute__((ext_vector_type(4)));  // 4 bf16 (8 B)
typedef float float4v __attribute__((ext_vector_type(4)));  // MFMA C/D

#define MFMA16(a, b, c) __builtin_amdgcn_mfma_f32_16x16x32_bf16(a, b, c, 0, 0, 0)

__device__ inline unsigned short bf16_rne(float f) {
  unsigned u = __builtin_bit_cast(unsigned, f);
  u += 0x7FFFu + ((u >> 16) & 1u);
  return (unsigned short)(u >> 16);
}

// hi = bf16 truncation, lo = bf16 RNE of residual.  hi*hi + hi*lo + lo*hi
// reconstructs the product to ~2^-15.5 rel.
__device__ inline void split4(float4 a, short4v& hi, short4v& lo) {
  float f[4] = {a.x, a.y, a.z, a.w};
#pragma unroll
  for (int j = 0; j < 4; ++j) {
    unsigned u = __builtin_bit_cast(unsigned, f[j]);
    unsigned short h = (unsigned short)(u >> 16);
    hi[j] = (short)h;
    float hf = __builtin_bit_cast(float, (unsigned)h << 16);
    lo[j] = (short)bf16_rne(f[j] - hf);
  }
}

__device__ inline void split8(float4 a, float4 b, short8& hi, short8& lo) {
  float f[8] = {a.x, a.y, a.z, a.w, b.x, b.y, b.z, b.w};
#pragma unroll
  for (int j = 0; j < 8; ++j) {
    unsigned u = __builtin_bit_cast(unsigned, f[j]);
    unsigned short h = (unsigned short)(u >> 16);
    hi[j] = (short)h;
    float hf = __builtin_bit_cast(float, (unsigned)h << 16);
    lo[j] = (short)bf16_rne(f[j] - hf);
  }
}

__device__ inline short8 pack4(const unsigned* p) {
  union { unsigned u[4]; short8 s; } t;
  t.u[0] = p[0]; t.u[1] = p[1]; t.u[2] = p[2]; t.u[3] = p[3];
  return t.s;  // u32 = 2 consecutive bf16 (low halfword = even k) = frag pair
}

// LDS-only barrier: waits for this wave's DS ops (lgkmcnt) but leaves global
// loads (vmcnt) IN FLIGHT across the barrier -- the T14 async-STAGE enabler.
// sched_barrier(0) fences stop the compiler from sinking pre-barrier loads
// or hoisting post-barrier consumers (round-3 lesson: source order needs
// teeth; guide rule #18).
__device__ inline void lds_barrier() {
  __builtin_amdgcn_sched_barrier(0);
  asm volatile("s_waitcnt lgkmcnt(0)" ::: "memory");
  __builtin_amdgcn_s_barrier();
  __builtin_amdgcn_sched_barrier(0);
}

// One block = one 128x128 attention group (b, idx, h), EIGHT waves, each
// owning 16 output rows.  Round-5 restructure: phase-scheduled staging.
//   t0:      issue Q,K,V,mask global loads (registers)
//   phase A: split K -> LDS planes, split Q -> frags        [lds_barrier]
//   phase B: score GEMM + softmax (mask already in regs)    [lds_barrier]
//   phase C: P -> LDS, V (loaded at t0) -> LDS              [__syncthreads]
//   phase D: PV GEMM, normalize, store
// V's global latency + convert cost hides under phases A-B instead of
// sitting on the critical path before the first barrier.
__global__ __launch_bounds__(512, 4) void st_attn(
    const float* __restrict__ Qp, const float* __restrict__ Kp,
    const float* __restrict__ Vp, const float* __restrict__ Mp,
    float* __restrict__ Op, int idx_stride, int row_stride) {
  // Pb is dual-purpose:
  //   phase A/B: K pre-split bf16 hi/lo planes, fragment-linear + XOR swizzle.
  //              hi plane = u16 [0, 8192), lo plane = u16 [8192, 16384).
  //   phase C/D: P (exp'd scores) bf16, row-major stride 130 (16,640 u16).
  __shared__ __align__(16) unsigned short Pb[128 * 130];
  // V^T as bf16: Vb[d][c], stride 130 halfwords.  Total 49,920 B.
  __shared__ __align__(16) unsigned short Vb[64 * 130];

  const int g = blockIdx.x;
  const int b = g >> 10;
  const int idx = (g >> 3) & 127;
  const int h = g & 7;
  const int base = b * (Nn * Ll * Hh * Ee) + idx * idx_stride + h * Ee;

  const int tid = threadIdx.x;
  const int wave = tid >> 6;   // 0..7
  const int lane = tid & 63;
  const int tx = lane & 15;    // MFMA m/n lane index
  const int quad = lane >> 4;  // MFMA k-chunk / row-quad
  const int rowbase = wave * 16;   // this wave's 16 output rows
  const int rowb = rowbase + quad * 4;  // C/D row = quad*4+e

  const bool has_mask = (Mp != nullptr);
  const int mb = b * (Nn * Nn);

  // ======== t0: issue ALL global loads into registers ======================
  // Order matters for vmcnt semantics: Q,K first (consumed in phase A, their
  // waits leave later loads outstanding), then V (consumed phase C), then
  // mask (consumed phase B).
  float4 qL[4], kL[4], vL[4];
#pragma unroll
  for (int it = 0; it < 4; ++it) {
    const int i4 = tid + it * 512;
    kL[it] = *(const float4*)(Kp + base + (i4 >> 4) * row_stride +
                              ((i4 & 15) << 2));
  }
  {
    const float* qr = Qp + base + (rowbase + tx) * row_stride;
#pragma unroll
    for (int ks = 0; ks < 2; ++ks) {
      qL[ks * 2 + 0] = *(const float4*)(qr + ks * 32 + quad * 8);
      qL[ks * 2 + 1] = *(const float4*)(qr + ks * 32 + quad * 8 + 4);
    }
  }
#pragma unroll
  for (int it = 0; it < 4; ++it) {
    const int i4 = tid + it * 512;
    vL[it] = *(const float4*)(Vp + base + (i4 >> 4) * row_stride +
                              ((i4 & 15) << 2));
  }
  float mv[8][4];
  if (has_mask) {
#pragma unroll
    for (int ct = 0; ct < 8; ++ct)
#pragma unroll
      for (int e = 0; e < 4; ++e)
        mv[ct][e] = Mp[mb + (rowb + e) * 128 + ct * 16 + tx];
  }

  // ======== phase A: K -> LDS planes (split), Q -> frags ===================
  // Element K[r][d]: fragment F = ((r>>4)*8+(d>>3))*16+(r&15); F' = F^(d>>3).
  // u16 index = F'*8 + (d&7); lo plane at +8192 u16.
#pragma unroll
  for (int it = 0; it < 4; ++it) {
    const int i4 = tid + it * 512;
    const int r = i4 >> 4;             // K row 0..127
    const int d0 = (i4 & 15) << 2;     // K col 0..60
    const int vs = d0 >> 3;            // ks*4+quad of this chunk, 0..7
    const int idxk =
        ((((r >> 4) * 8 + vs) * 16 + (r & 15)) ^ vs) * 8 + (d0 & 7);
    short4v h4, l4;
    split4(kL[it], h4, l4);
    *(short4v*)(Pb + idxk) = h4;
    *(short4v*)(Pb + idxk + 8192) = l4;
  }

  short8 qhi[2], qlo[2];
#pragma unroll
  for (int ks = 0; ks < 2; ++ks)
    split8(qL[ks * 2 + 0], qL[ks * 2 + 1], qhi[ks], qlo[ks]);

  lds_barrier();  // A: K planes staged; V + mask loads still in flight

  // ======== phase B: score GEMM + softmax ==================================
  float4v acc[8];
#pragma unroll
  for (int ct = 0; ct < 8; ++ct) acc[ct] = (float4v)(0.0f);

  const short8* KS8 = (const short8*)Pb;
#pragma unroll
  for (int ct = 0; ct < 8; ++ct) {
#pragma unroll
    for (int ks = 0; ks < 2; ++ks) {
      const int vs = ks * 4 + quad;
      const int fi = (((ct * 8 + vs) * 16 + tx) ^ vs);
      const short8 khi = KS8[fi];
      const short8 klo = KS8[fi + 1024];  // lo plane: +1024 frags
      acc[ct] = MFMA16(qhi[ks], khi, acc[ct]);
      acc[ct] = MFMA16(qhi[ks], klo, acc[ct]);
      acc[ct] = MFMA16(qlo[ks], khi, acc[ct]);
    }
  }

  float rowsum[4] = {0.f, 0.f, 0.f, 0.f};
#pragma unroll
  for (int ct = 0; ct < 8; ++ct) {
#pragma unroll
    for (int e = 0; e < 4; ++e) {
      float p = acc[ct][e] * SCALE;
      if (has_mask) p *= mv[ct][e];
      p = __expf(p);
      rowsum[e] += p;   // exact fp32 denominator (pre-rounding)
      acc[ct][e] = p;   // keep P in registers until Pb is free
    }
  }

  // Row sums complete across the 16 tx lanes of each quad group.
  float inv[4];
#pragma unroll
  for (int e = 0; e < 4; ++e) {
    float s = rowsum[e];
#pragma unroll
    for (int d = 1; d < 16; d <<= 1) s += __shfl_xor(s, d);
    inv[e] = 1.0f / s;
  }

  lds_barrier();  // B: all waves done reading K planes -> Pb reusable
                  //    (V loads STILL in flight / just landing)

  // ======== phase C: P -> LDS, V -> LDS ====================================
#pragma unroll
  for (int ct = 0; ct < 8; ++ct) {
    const int col = ct * 16 + tx;
#pragma unroll
    for (int e = 0; e < 4; ++e)
      Pb[(rowb + e) * 130 + col] = bf16_rne(acc[ct][e]);
  }

  // Consume V (issued at t0; HBM latency hidden under phases A-B).
#pragma unroll
  for (int it = 0; it < 4; ++it) {
    const int i4 = tid + it * 512;
    const int c = i4 >> 4;             // V row 0..127
    const int d0 = (i4 & 15) << 2;     // V col 0..60
    const float4 v = vL[it];
    Vb[(d0 + 0) * 130 + c] = bf16_rne(v.x);
    Vb[(d0 + 1) * 130 + c] = bf16_rne(v.y);
    Vb[(d0 + 2) * 130 + c] = bf16_rne(v.z);
    Vb[(d0 + 3) * 130 + c] = bf16_rne(v.w);
  }

  __syncthreads();  // C: P + V staged (nothing left outstanding to preserve)

  // ======== phase D: PV GEMM, normalize, store =============================
  float4v accO[4];
#pragma unroll
  for (int dt = 0; dt < 4; ++dt) accO[dt] = (float4v)(0.0f);

#pragma unroll
  for (int ks = 0; ks < 4; ++ks) {
    const unsigned* pw =
        (const unsigned*)Pb + (rowbase + tx) * 65 + ks * 16 + quad * 4;
    const short8 pA = pack4(pw);
#pragma unroll
    for (int dt = 0; dt < 4; ++dt) {
      const unsigned* vw =
          (const unsigned*)Vb + (dt * 16 + tx) * 65 + ks * 16 + quad * 4;
      const short8 vB = pack4(vw);
      accO[dt] = MFMA16(pA, vB, accO[dt]);
    }
  }

#pragma unroll
  for (int dt = 0; dt < 4; ++dt) {
#pragma unroll
    for (int e = 0; e < 4; ++e) {
      Op[base + (rowb + e) * row_stride + dt * 16 + tx] =
          accO[dt][e] * inv[e];
    }
  }
}

extern "C" void kernel_launch(void* const* d_in, const int* in_sizes, int n_in,
                              void* d_out, int out_size, void* d_ws,
                              size_t ws_size, hipStream_t stream) {
  const float* Q = (const float*)d_in[0];
  const float* K = (const float*)d_in[1];
  const float* V = (const float*)d_in[2];
  const float* M = (const float*)d_in[3];
  float* out = (float*)d_out;
  float* Vt = (float*)d_ws;  // 64 MiB intermediate V_t in workspace

  dim3 grid(Bb * Nn * Hh), blk(512);  // 2048 blocks x 8 waves
  // Temporal: per (b,n,h), rows = l
  st_attn<<<grid, blk, 0, stream>>>(Q, K, V, nullptr, Vt,
                                    Ll * Hh * Ee /*n stride*/,
                                    Hh * Ee /*l stride*/);
  // Spatial: per (b,l,h), rows = n, V operand = V_t
  st_attn<<<grid, blk, 0, stream>>>(Q, K, Vt, M, out, Hh * Ee /*l stride*/,
                                    Ll * Hh * Ee /*n stride*/);
}

// Round 6
// 270.977 us; speedup vs baseline: 1.1208x; 1.0177x over previous
//
#include <hip/hip_runtime.h>

// Problem constants (fixed by setup_inputs)
static constexpr int Bb = 2, Nn = 128, Ll = 128, Hh = 8, Ee = 64;
static constexpr float SCALE = 0.125f;  // 1/sqrt(E)

typedef short short8 __attribute__((ext_vector_type(8)));   // 8 bf16 in 4 VGPRs
typedef short short4v __attribute__((ext_vector_type(4)));  // 4 bf16 (8 B)
typedef float float4v __attribute__((ext_vector_type(4)));  // MFMA C/D

#define MFMA16(a, b, c) __builtin_amdgcn_mfma_f32_16x16x32_bf16(a, b, c, 0, 0, 0)

// ---- inline-asm loads: the compiler cannot sink/reschedule these ----------
// All staged loads go through here so vmcnt counting is exact.  Volatile +
// memory clobber keeps them in program order at the t0 issue point; results
// live in VGPRs until the counted s_waitcnt releases them (T4/T14).
__device__ inline float4 gload4(const float* p) {
  float4 r;
  asm volatile("global_load_dwordx4 %0, %1, off" : "=v"(r) : "v"(p) : "memory");
  return r;
}
__device__ inline float gload1(const float* p) {
  float r;
  asm volatile("global_load_dword %0, %1, off" : "=v"(r) : "v"(p) : "memory");
  return r;
}
#define WAIT_VM(N)                                    \
  do {                                                \
    asm volatile("s_waitcnt vmcnt(" #N ")" ::: "memory"); \
    __builtin_amdgcn_sched_barrier(0);                \
  } while (0)

__device__ inline unsigned short bf16_rne(float f) {
  unsigned u = __builtin_bit_cast(unsigned, f);
  u += 0x7FFFu + ((u >> 16) & 1u);
  return (unsigned short)(u >> 16);
}

// hi = bf16 truncation, lo = bf16 RNE of residual.  hi*hi + hi*lo + lo*hi
// reconstructs the product to ~2^-15.5 rel.
__device__ inline void split4(float4 a, short4v& hi, short4v& lo) {
  float f[4] = {a.x, a.y, a.z, a.w};
#pragma unroll
  for (int j = 0; j < 4; ++j) {
    unsigned u = __builtin_bit_cast(unsigned, f[j]);
    unsigned short h = (unsigned short)(u >> 16);
    hi[j] = (short)h;
    float hf = __builtin_bit_cast(float, (unsigned)h << 16);
    lo[j] = (short)bf16_rne(f[j] - hf);
  }
}

__device__ inline void split8(float4 a, float4 b, short8& hi, short8& lo) {
  float f[8] = {a.x, a.y, a.z, a.w, b.x, b.y, b.z, b.w};
#pragma unroll
  for (int j = 0; j < 8; ++j) {
    unsigned u = __builtin_bit_cast(unsigned, f[j]);
    unsigned short h = (unsigned short)(u >> 16);
    hi[j] = (short)h;
    float hf = __builtin_bit_cast(float, (unsigned)h << 16);
    lo[j] = (short)bf16_rne(f[j] - hf);
  }
}

__device__ inline short8 pack4(const unsigned* p) {
  union { unsigned u[4]; short8 s; } t;
  t.u[0] = p[0]; t.u[1] = p[1]; t.u[2] = p[2]; t.u[3] = p[3];
  return t.s;  // u32 = 2 consecutive bf16 (low halfword = even k) = frag pair
}

// LDS-only barrier: waits for this wave's DS ops (lgkmcnt) but leaves global
// loads (vmcnt) IN FLIGHT across the barrier.
__device__ inline void lds_barrier() {
  __builtin_amdgcn_sched_barrier(0);
  asm volatile("s_waitcnt lgkmcnt(0)" ::: "memory");
  __builtin_amdgcn_s_barrier();
  __builtin_amdgcn_sched_barrier(0);
}

// One block = one 128x128 attention group (b, idx, h), EIGHT waves, each
// owning 16 output rows.  Round-6: ALL staging loads issued at t0 via
// inline asm (44/12 loads in flight per thread), consumed under counted
// vmcnt waits:
//   issue order: K(4), Q(4), [mask(32)], V(4)
//   phase A: vmcnt(36|4)  -> K,Q done; split K->LDS planes, Q->frags  [ldsbar]
//   phase B: QK MFMA; vmcnt(4|--) -> mask done; softmax               [ldsbar]
//   phase C: P->LDS; vmcnt(0) -> V done; V->LDS                  [syncthreads]
//   phase D: PV MFMA, normalize, store
__device__ __forceinline__ void st_attn_body(
    const float* __restrict__ Qp, const float* __restrict__ Kp,
    const float* __restrict__ Vp, const float* __restrict__ Mp,
    float* __restrict__ Op, int idx_stride, int row_stride, bool HAS_MASK);

template <bool HAS_MASK>
__global__ __launch_bounds__(512, 3) void st_attn(
    const float* __restrict__ Qp, const float* __restrict__ Kp,
    const float* __restrict__ Vp, const float* __restrict__ Mp,
    float* __restrict__ Op, int idx_stride, int row_stride) {
  // Pb is dual-purpose:
  //   phase A/B: K pre-split bf16 hi/lo planes, fragment-linear + XOR swizzle.
  //              hi plane = u16 [0, 8192), lo plane = u16 [8192, 16384).
  //   phase C/D: P (exp'd scores) bf16, row-major stride 130 (16,640 u16).
  __shared__ __align__(16) unsigned short Pb[128 * 130];
  // V^T as bf16: Vb[d][c], stride 130 halfwords.  Total 49,920 B.
  __shared__ __align__(16) unsigned short Vb[64 * 130];

  const int g = blockIdx.x;
  const int b = g >> 10;
  const int idx = (g >> 3) & 127;
  const int h = g & 7;
  const int base = b * (Nn * Ll * Hh * Ee) + idx * idx_stride + h * Ee;

  const int tid = threadIdx.x;
  const int wave = tid >> 6;   // 0..7
  const int lane = tid & 63;
  const int tx = lane & 15;    // MFMA m/n lane index
  const int quad = lane >> 4;  // MFMA k-chunk / row-quad
  const int rowbase = wave * 16;        // this wave's 16 output rows
  const int rowb = rowbase + quad * 4;  // C/D row = quad*4+e

  const int mb = b * (Nn * Nn);

  // ======== t0: issue ALL global loads via asm (fixed order) ===============
  float4 kL[4], qL[4], vL[4];
  float mv[8][4];
#pragma unroll
  for (int it = 0; it < 4; ++it) {
    const int i4 = tid + it * 512;
    kL[it] = gload4(Kp + base + (i4 >> 4) * row_stride + ((i4 & 15) << 2));
  }
  {
    const float* qr = Qp + base + (rowbase + tx) * row_stride;
#pragma unroll
    for (int ks = 0; ks < 2; ++ks) {
      qL[ks * 2 + 0] = gload4(qr + ks * 32 + quad * 8);
      qL[ks * 2 + 1] = gload4(qr + ks * 32 + quad * 8 + 4);
    }
  }
  if constexpr (HAS_MASK) {
#pragma unroll
    for (int ct = 0; ct < 8; ++ct)
#pragma unroll
      for (int e = 0; e < 4; ++e)
        mv[ct][e] = gload1(Mp + mb + (rowb + e) * 128 + ct * 16 + tx);
  }
#pragma unroll
  for (int it = 0; it < 4; ++it) {
    const int i4 = tid + it * 512;
    vL[it] = gload4(Vp + base + (i4 >> 4) * row_stride + ((i4 & 15) << 2));
  }
  // outstanding now: HAS_MASK ? 44 : 12

  // ======== phase A: K -> LDS planes (split), Q -> frags ===================
  if constexpr (HAS_MASK) WAIT_VM(36);  // K+Q landed; mask+V still flying
  else                    WAIT_VM(4);   // K+Q landed; V still flying

  // Element K[r][d]: fragment F = ((r>>4)*8+(d>>3))*16+(r&15); F' = F^(d>>3).
  // u16 index = F'*8 + (d&7); lo plane at +8192 u16.
#pragma unroll
  for (int it = 0; it < 4; ++it) {
    const int i4 = tid + it * 512;
    const int r = i4 >> 4;             // K row 0..127
    const int d0 = (i4 & 15) << 2;     // K col 0..60
    const int vs = d0 >> 3;            // ks*4+quad of this chunk, 0..7
    const int idxk =
        ((((r >> 4) * 8 + vs) * 16 + (r & 15)) ^ vs) * 8 + (d0 & 7);
    short4v h4, l4;
    split4(kL[it], h4, l4);
    *(short4v*)(Pb + idxk) = h4;
    *(short4v*)(Pb + idxk + 8192) = l4;
  }

  short8 qhi[2], qlo[2];
#pragma unroll
  for (int ks = 0; ks < 2; ++ks)
    split8(qL[ks * 2 + 0], qL[ks * 2 + 1], qhi[ks], qlo[ks]);

  lds_barrier();  // A: K planes staged; mask + V loads still in flight

  // ======== phase B: score GEMM + softmax ==================================
  float4v acc[8];
#pragma unroll
  for (int ct = 0; ct < 8; ++ct) acc[ct] = (float4v)(0.0f);

  const short8* KS8 = (const short8*)Pb;
#pragma unroll
  for (int ct = 0; ct < 8; ++ct) {
#pragma unroll
    for (int ks = 0; ks < 2; ++ks) {
      const int vs = ks * 4 + quad;
      const int fi = (((ct * 8 + vs) * 16 + tx) ^ vs);
      const short8 khi = KS8[fi];
      const short8 klo = KS8[fi + 1024];  // lo plane: +1024 frags
      acc[ct] = MFMA16(qhi[ks], khi, acc[ct]);
      acc[ct] = MFMA16(qhi[ks], klo, acc[ct]);
      acc[ct] = MFMA16(qlo[ks], khi, acc[ct]);
    }
  }

  if constexpr (HAS_MASK) WAIT_VM(4);  // mask landed; V still flying

  float rowsum[4] = {0.f, 0.f, 0.f, 0.f};
#pragma unroll
  for (int ct = 0; ct < 8; ++ct) {
#pragma unroll
    for (int e = 0; e < 4; ++e) {
      float p = acc[ct][e] * SCALE;
      if (HAS_MASK) p *= mv[ct][e];
      p = __expf(p);
      rowsum[e] += p;   // exact fp32 denominator (pre-rounding)
      acc[ct][e] = p;   // keep P in registers until Pb is free
    }
  }

  // Row sums complete across the 16 tx lanes of each quad group.
  float inv[4];
#pragma unroll
  for (int e = 0; e < 4; ++e) {
    float s = rowsum[e];
#pragma unroll
    for (int d = 1; d < 16; d <<= 1) s += __shfl_xor(s, d);
    inv[e] = 1.0f / s;
  }

  lds_barrier();  // B: all waves done reading K planes -> Pb reusable
                  //    (V loads STILL in flight / just landing)

  // ======== phase C: P -> LDS, V -> LDS ====================================
#pragma unroll
  for (int ct = 0; ct < 8; ++ct) {
    const int col = ct * 16 + tx;
#pragma unroll
    for (int e = 0; e < 4; ++e)
      Pb[(rowb + e) * 130 + col] = bf16_rne(acc[ct][e]);
  }

  WAIT_VM(0);  // V landed (latency hidden under phases A-B)
#pragma unroll
  for (int it = 0; it < 4; ++it) {
    const int i4 = tid + it * 512;
    const int c = i4 >> 4;             // V row 0..127
    const int d0 = (i4 & 15) << 2;     // V col 0..60
    const float4 v = vL[it];
    Vb[(d0 + 0) * 130 + c] = bf16_rne(v.x);
    Vb[(d0 + 1) * 130 + c] = bf16_rne(v.y);
    Vb[(d0 + 2) * 130 + c] = bf16_rne(v.z);
    Vb[(d0 + 3) * 130 + c] = bf16_rne(v.w);
  }

  __syncthreads();  // C: P + V staged

  // ======== phase D: PV GEMM, normalize, store =============================
  float4v accO[4];
#pragma unroll
  for (int dt = 0; dt < 4; ++dt) accO[dt] = (float4v)(0.0f);

#pragma unroll
  for (int ks = 0; ks < 4; ++ks) {
    const unsigned* pw =
        (const unsigned*)Pb + (rowbase + tx) * 65 + ks * 16 + quad * 4;
    const short8 pA = pack4(pw);
#pragma unroll
    for (int dt = 0; dt < 4; ++dt) {
      const unsigned* vw =
          (const unsigned*)Vb + (dt * 16 + tx) * 65 + ks * 16 + quad * 4;
      const short8 vB = pack4(vw);
      accO[dt] = MFMA16(pA, vB, accO[dt]);
    }
  }

#pragma unroll
  for (int dt = 0; dt < 4; ++dt) {
#pragma unroll
    for (int e = 0; e < 4; ++e) {
      Op[base + (rowb + e) * row_stride + dt * 16 + tx] =
          accO[dt][e] * inv[e];
    }
  }
}

extern "C" void kernel_launch(void* const* d_in, const int* in_sizes, int n_in,
                              void* d_out, int out_size, void* d_ws,
                              size_t ws_size, hipStream_t stream) {
  const float* Q = (const float*)d_in[0];
  const float* K = (const float*)d_in[1];
  const float* V = (const float*)d_in[2];
  const float* M = (const float*)d_in[3];
  float* out = (float*)d_out;
  float* Vt = (float*)d_ws;  // 64 MiB intermediate V_t in workspace

  dim3 grid(Bb * Nn * Hh), blk(512);  // 2048 blocks x 8 waves
  // Temporal: per (b,n,h), rows = l
  st_attn<false><<<grid, blk, 0, stream>>>(Q, K, V, nullptr, Vt,
                                           Ll * Hh * Ee /*n stride*/,
                                           Hh * Ee /*l stride*/);
  // Spatial: per (b,l,h), rows = n, V operand = V_t
  st_attn<true><<<grid, blk, 0, stream>>>(Q, K, Vt, M, out,
                                          Hh * Ee /*l stride*/,
                                          Ll * Hh * Ee /*n stride*/);
}

// Round 8
// 264.729 us; speedup vs baseline: 1.1473x; 1.0236x over previous
//
#include <hip/hip_runtime.h>

// Problem constants (fixed by setup_inputs)
static constexpr int Bb = 2, Nn = 128, Ll = 128, Hh = 8, Ee = 64;
static constexpr float SCALE = 0.125f;  // 1/sqrt(E)

typedef short short8 __attribute__((ext_vector_type(8)));   // 8 bf16 in 4 VGPRs
typedef short short4v __attribute__((ext_vector_type(4)));  // 4 bf16 (8 B)
typedef float float4v __attribute__((ext_vector_type(4)));  // MFMA C/D

#define MFMA16(a, b, c) __builtin_amdgcn_mfma_f32_16x16x32_bf16(a, b, c, 0, 0, 0)

// ---- inline-asm staged loads: exact vmcnt counting, compiler can't move ---
__device__ inline float4 gload4(const float* p) {
  float4 r;
  asm volatile("global_load_dwordx4 %0, %1, off" : "=v"(r) : "v"(p) : "memory");
  return r;
}
__device__ inline float gload1(const float* p) {
  float r;
  asm volatile("global_load_dword %0, %1, off" : "=v"(r) : "v"(p) : "memory");
  return r;
}
#define WAIT_VM(N)                                        \
  do {                                                    \
    asm volatile("s_waitcnt vmcnt(" #N ")" ::: "memory"); \
    __builtin_amdgcn_sched_barrier(0);                    \
  } while (0)

__device__ inline unsigned short bf16_rne(float f) {
  unsigned u = __builtin_bit_cast(unsigned, f);
  u += 0x7FFFu + ((u >> 16) & 1u);
  return (unsigned short)(u >> 16);
}

// hi = bf16 truncation, lo = bf16 RNE of residual.  hi*hi + hi*lo + lo*hi
// reconstructs the product to ~2^-15.5 rel.
__device__ inline void split4(float4 a, short4v& hi, short4v& lo) {
  float f[4] = {a.x, a.y, a.z, a.w};
#pragma unroll
  for (int j = 0; j < 4; ++j) {
    unsigned u = __builtin_bit_cast(unsigned, f[j]);
    unsigned short h = (unsigned short)(u >> 16);
    hi[j] = (short)h;
    float hf = __builtin_bit_cast(float, (unsigned)h << 16);
    lo[j] = (short)bf16_rne(f[j] - hf);
  }
}

__device__ inline void split8(float4 a, float4 b, short8& hi, short8& lo) {
  float f[8] = {a.x, a.y, a.z, a.w, b.x, b.y, b.z, b.w};
#pragma unroll
  for (int j = 0; j < 8; ++j) {
    unsigned u = __builtin_bit_cast(unsigned, f[j]);
    unsigned short h = (unsigned short)(u >> 16);
    hi[j] = (short)h;
    float hf = __builtin_bit_cast(float, (unsigned)h << 16);
    lo[j] = (short)bf16_rne(f[j] - hf);
  }
}

__device__ inline short8 pack4(const unsigned* p) {
  union { unsigned u[4]; short8 s; } t;
  t.u[0] = p[0]; t.u[1] = p[1]; t.u[2] = p[2]; t.u[3] = p[3];
  return t.s;  // u32 = 2 consecutive bf16 (low halfword = even k) = frag pair
}

// LDS-only barrier: waits for this wave's DS ops (lgkmcnt) but leaves global
// loads (vmcnt) IN FLIGHT across the barrier.
__device__ inline void lds_barrier() {
  __builtin_amdgcn_sched_barrier(0);
  asm volatile("s_waitcnt lgkmcnt(0)" ::: "memory");
  __builtin_amdgcn_s_barrier();
  __builtin_amdgcn_sched_barrier(0);
}

// One block = one 128x128 attention group (b, idx, h), 8 waves x 16 rows.
//   P[r][c] = exp(SCALE * (mask?) * dot(Q[r],K[c]));  Out = (P*V) / rowsum(P)
//
// Round-8 byte-reduction:
//   V_t intermediate is bf16 in layout [B, L, H, M, E] (was fp32 [B,N,L,H,E]):
//     - temporal writes 33.5 MB instead of 67 (identical numerics: V_t was
//       rounded to bf16 before the spatial PV GEMM anyway)
//     - spatial reads its whole V_t slice as ONE contiguous 16 KB stream
//   Spatial mask loads join the asm-load group (issued last) so counted
//   vmcnt is airtight: order K(4),Q(4),V(2),M(32); vmcnt(34) -> K+Q landed,
//   vmcnt(0) before softmax -> mask (and V) landed.
//
// SPATIAL=false (temporal): idx=n, rows=l, V=fp32 in [B,N,L,H,E], out=Vt bf16
// SPATIAL=true  (spatial) : idx=l, rows=n, V=Vt bf16, mask, out=fp32
template <bool SPATIAL>
__global__ __launch_bounds__(512, 3) void st_attn(
    const float* __restrict__ Qp, const float* __restrict__ Kp,
    const void* __restrict__ Vp, const float* __restrict__ Mp,
    void* __restrict__ Op, int idx_stride, int row_stride) {
  // Pb dual-purpose: phase A/B = K bf16 hi/lo planes (u16 [0,8192) hi,
  // [8192,16384) lo, fragment-linear + XOR swizzle); phase C/D = P bf16,
  // row-major stride 130.
  __shared__ __align__(16) unsigned short Pb[128 * 130];
  // V^T bf16: Vb[d][c], stride 130.  Total LDS 49,920 B -> 3 blocks/CU.
  __shared__ __align__(16) unsigned short Vb[64 * 130];

  const int g = blockIdx.x;
  const int b = g >> 10;
  const int idx = (g >> 3) & 127;
  const int h = g & 7;
  const int base = b * (Nn * Ll * Hh * Ee) + idx * idx_stride + h * Ee;

  const int tid = threadIdx.x;
  const int wave = tid >> 6;   // 0..7
  const int lane = tid & 63;
  const int tx = lane & 15;    // MFMA m/n lane index
  const int quad = lane >> 4;  // MFMA k-chunk / row-quad
  const int rowbase = wave * 16;        // this wave's 16 output rows
  const int rowb = rowbase + quad * 4;  // C/D row = quad*4+e
  const int mb = b * (Nn * Nn);

  // ======== t0: issue ALL staged loads via asm (fixed order) ===============
  float4 kL[4], qL[4], vL[4];
  float mv[8][4];
#pragma unroll
  for (int it = 0; it < 4; ++it) {
    const int i4 = tid + it * 512;
    kL[it] = gload4(Kp + base + (i4 >> 4) * row_stride + ((i4 & 15) << 2));
  }
  {
    const float* qr = Qp + base + (rowbase + tx) * row_stride;
#pragma unroll
    for (int ks = 0; ks < 2; ++ks) {
      qL[ks * 2 + 0] = gload4(qr + ks * 32 + quad * 8);
      qL[ks * 2 + 1] = gload4(qr + ks * 32 + quad * 8 + 4);
    }
  }
  if constexpr (SPATIAL) {
    // V_t slice [b, idx=l, h, :, :] = 8192 bf16, contiguous.
    const unsigned short* Vt = (const unsigned short*)Vp;
    const unsigned short* vsl =
        Vt + ((b * Ll + idx) * Hh + h) * (Nn * Ee);
#pragma unroll
    for (int it = 0; it < 2; ++it) {
      const int i8 = tid + it * 512;  // 0..1023 chunks of 8 bf16
      vL[it] = gload4((const float*)(vsl + i8 * 8));
    }
    // Mask: 32 loads, issued LAST (youngest).
#pragma unroll
    for (int ct = 0; ct < 8; ++ct)
#pragma unroll
      for (int e = 0; e < 4; ++e)
        mv[ct][e] = gload1(Mp + mb + (rowb + e) * 128 + ct * 16 + tx);
    // outstanding: 4K + 4Q + 2V + 32M = 42
  } else {
    const float* Vf = (const float*)Vp;
#pragma unroll
    for (int it = 0; it < 4; ++it) {
      const int i4 = tid + it * 512;
      vL[it] = gload4(Vf + base + (i4 >> 4) * row_stride + ((i4 & 15) << 2));
    }
    // outstanding: 4K + 4Q + 4V = 12
  }

  // ======== phase A: K -> LDS planes (split), Q -> frags ===================
  if constexpr (SPATIAL) WAIT_VM(34);  // K+Q (oldest 8) landed
  else                   WAIT_VM(4);   // K+Q landed; V flying

  // Element K[r][d]: fragment F = ((r>>4)*8+(d>>3))*16+(r&15); F' = F^(d>>3).
  // u16 index = F'*8 + (d&7); lo plane at +8192 u16.
#pragma unroll
  for (int it = 0; it < 4; ++it) {
    const int i4 = tid + it * 512;
    const int r = i4 >> 4;             // K row 0..127
    const int d0 = (i4 & 15) << 2;     // K col 0..60
    const int vs = d0 >> 3;            // ks*4+quad of this chunk, 0..7
    const int idxk =
        ((((r >> 4) * 8 + vs) * 16 + (r & 15)) ^ vs) * 8 + (d0 & 7);
    short4v h4, l4;
    split4(kL[it], h4, l4);
    *(short4v*)(Pb + idxk) = h4;
    *(short4v*)(Pb + idxk + 8192) = l4;
  }

  short8 qhi[2], qlo[2];
#pragma unroll
  for (int ks = 0; ks < 2; ++ks)
    split8(qL[ks * 2 + 0], qL[ks * 2 + 1], qhi[ks], qlo[ks]);

  lds_barrier();  // A: K planes staged; V (+mask) loads still in flight

  // ======== phase B: score GEMM + softmax ==================================
  float4v acc[8];
#pragma unroll
  for (int ct = 0; ct < 8; ++ct) acc[ct] = (float4v)(0.0f);

  const short8* KS8 = (const short8*)Pb;
#pragma unroll
  for (int ct = 0; ct < 8; ++ct) {
#pragma unroll
    for (int ks = 0; ks < 2; ++ks) {
      const int vs = ks * 4 + quad;
      const int fi = (((ct * 8 + vs) * 16 + tx) ^ vs);
      const short8 khi = KS8[fi];
      const short8 klo = KS8[fi + 1024];  // lo plane: +1024 frags
      acc[ct] = MFMA16(qhi[ks], khi, acc[ct]);
      acc[ct] = MFMA16(qhi[ks], klo, acc[ct]);
      acc[ct] = MFMA16(qlo[ks], khi, acc[ct]);
    }
  }

  if constexpr (SPATIAL) WAIT_VM(0);  // mask + V landed (hidden under QK)

  float rowsum[4] = {0.f, 0.f, 0.f, 0.f};
#pragma unroll
  for (int ct = 0; ct < 8; ++ct) {
#pragma unroll
    for (int e = 0; e < 4; ++e) {
      float p = acc[ct][e] * SCALE;
      if (SPATIAL) p *= mv[ct][e];
      p = __expf(p);
      rowsum[e] += p;   // exact fp32 denominator (pre-rounding)
      acc[ct][e] = p;   // keep P in registers until Pb is free
    }
  }

  float inv[4];
#pragma unroll
  for (int e = 0; e < 4; ++e) {
    float s = rowsum[e];
#pragma unroll
    for (int d = 1; d < 16; d <<= 1) s += __shfl_xor(s, d);
    inv[e] = 1.0f / s;
  }

  lds_barrier();  // B: all waves done reading K planes -> Pb reusable

  // ======== phase C: P -> LDS, V -> LDS ====================================
#pragma unroll
  for (int ct = 0; ct < 8; ++ct) {
    const int col = ct * 16 + tx;
#pragma unroll
    for (int e = 0; e < 4; ++e)
      Pb[(rowb + e) * 130 + col] = bf16_rne(acc[ct][e]);
  }

  if constexpr (SPATIAL) {
    // V_t already bf16: unpack 8 bf16 per chunk into Vb[d][c=m].
#pragma unroll
    for (int it = 0; it < 2; ++it) {
      const int i8 = tid + it * 512;
      const int m = i8 >> 3;            // V_t row (node m) 0..127
      const int e0 = (i8 & 7) * 8;      // dim 0..56
      union { float4 f; unsigned short u[8]; } t;
      t.f = vL[it];
#pragma unroll
      for (int j = 0; j < 8; ++j) Vb[(e0 + j) * 130 + m] = t.u[j];
    }
  } else {
    WAIT_VM(0);  // V landed (latency hidden under phases A-B)
#pragma unroll
    for (int it = 0; it < 4; ++it) {
      const int i4 = tid + it * 512;
      const int c = i4 >> 4;             // V row 0..127
      const int d0 = (i4 & 15) << 2;     // V col 0..60
      const float4 v = vL[it];
      Vb[(d0 + 0) * 130 + c] = bf16_rne(v.x);
      Vb[(d0 + 1) * 130 + c] = bf16_rne(v.y);
      Vb[(d0 + 2) * 130 + c] = bf16_rne(v.z);
      Vb[(d0 + 3) * 130 + c] = bf16_rne(v.w);
    }
  }

  __syncthreads();  // C: P + V staged

  // ======== phase D: PV GEMM, normalize, store =============================
  float4v accO[4];
#pragma unroll
  for (int dt = 0; dt < 4; ++dt) accO[dt] = (float4v)(0.0f);

#pragma unroll
  for (int ks = 0; ks < 4; ++ks) {
    const unsigned* pw =
        (const unsigned*)Pb + (rowbase + tx) * 65 + ks * 16 + quad * 4;
    const short8 pA = pack4(pw);
#pragma unroll
    for (int dt = 0; dt < 4; ++dt) {
      const unsigned* vw =
          (const unsigned*)Vb + (dt * 16 + tx) * 65 + ks * 16 + quad * 4;
      const short8 vB = pack4(vw);
      accO[dt] = MFMA16(pA, vB, accO[dt]);
    }
  }

  if constexpr (SPATIAL) {
    float* O = (float*)Op;
#pragma unroll
    for (int dt = 0; dt < 4; ++dt)
#pragma unroll
      for (int e = 0; e < 4; ++e)
        O[base + (rowb + e) * row_stride + dt * 16 + tx] =
            accO[dt][e] * inv[e];
  } else {
    // V_t out: bf16, layout [B, L, H, M, E]; row = l, idx = n.
    unsigned short* O = (unsigned short*)Op;
#pragma unroll
    for (int dt = 0; dt < 4; ++dt)
#pragma unroll
      for (int e = 0; e < 4; ++e)
        O[((b * Ll + (rowb + e)) * Hh + h) * (Nn * Ee) + idx * Ee + dt * 16 +
          tx] = bf16_rne(accO[dt][e] * inv[e]);
  }
}

extern "C" void kernel_launch(void* const* d_in, const int* in_sizes, int n_in,
                              void* d_out, int out_size, void* d_ws,
                              size_t ws_size, hipStream_t stream) {
  const float* Q = (const float*)d_in[0];
  const float* K = (const float*)d_in[1];
  const float* V = (const float*)d_in[2];
  const float* M = (const float*)d_in[3];
  float* out = (float*)d_out;
  unsigned short* Vt = (unsigned short*)d_ws;  // 33.5 MiB bf16 [B,L,H,M,E]

  dim3 grid(Bb * Nn * Hh), blk(512);  // 2048 blocks x 8 waves
  // Temporal: per (b,n,h), rows = l
  st_attn<false><<<grid, blk, 0, stream>>>(Q, K, (const void*)V, nullptr,
                                           (void*)Vt, Ll * Hh * Ee /*n*/,
                                           Hh * Ee /*l*/);
  // Spatial: per (b,l,h), rows = n, V operand = V_t bf16
  st_attn<true><<<grid, blk, 0, stream>>>(Q, K, (const void*)Vt, M,
                                          (void*)out, Hh * Ee /*l*/,
                                          Ll * Hh * Ee /*n*/);
}